// Round 5
// baseline (766.841 us; speedup 1.0000x reference)
//
#include <hip/hip_runtime.h>
#include <hip/hip_bf16.h>
#include <stdint.h>

#define S_LEN 256
#define BATCH 64
#define HD 256
#define NT 9
#define NTOK (S_LEN*BATCH)   // 16384

#define NREG 96              // w_hh pairs in VGPRs per thread (gates i,f,g)
#define NLDSROW 16           // uint2 rows in LDS (gate o: 32 pairs)

typedef _Float16 hf2 __attribute__((ext_vector_type(2)));
typedef short bf16x8 __attribute__((ext_vector_type(8)));
typedef float f32x4 __attribute__((ext_vector_type(4)));

__device__ __forceinline__ float sigf(float x){ return 1.f/(1.f+__expf(-x)); }
__device__ __forceinline__ float tanh_(float x){ return 1.f - 2.f/(__expf(2.f*x)+1.f); }
__device__ __forceinline__ float wredsum(float v){
#pragma unroll
  for (int s = 32; s > 0; s >>= 1) v += __shfl_xor(v, s);
  return v;
}
__device__ __forceinline__ uint16_t f2b(float f){
  __hip_bfloat16 h = __float2bfloat16(f);
  return *(uint16_t*)&h;
}
__device__ __forceinline__ float b2f(uint16_t u){
  union{uint32_t i; float f;} a; a.i = ((uint32_t)u)<<16; return a.f;
}

__device__ __forceinline__ float dot2p(uint32_t w, uint32_t h, float acc){
#if __has_builtin(__builtin_amdgcn_fdot2)
  return __builtin_amdgcn_fdot2(__builtin_bit_cast(hf2, w), __builtin_bit_cast(hf2, h), acc, false);
#else
  hf2 wv = __builtin_bit_cast(hf2, w), hv = __builtin_bit_cast(hf2, h);
  return acc + (float)wv.x*(float)hv.x + (float)wv.y*(float)hv.y;
#endif
}

// ---- prep: wih16[n][k] = bf16(w_ih_dir[g][k]) (n = dir*1024+g); bias[n] = b_ih+b_hh ----
__global__ void prep2(const float* __restrict__ wihf, const float* __restrict__ wihb,
                      const float* __restrict__ bif, const float* __restrict__ bhf,
                      const float* __restrict__ bib, const float* __restrict__ bhb,
                      uint16_t* __restrict__ wih16, float* __restrict__ bias){
  int idx = blockIdx.x*256 + threadIdx.x;       // < 2048*256
  int n = idx >> 8;
  int k = idx & 255;
  const float* w = (n < 1024) ? wihf : wihb;
  int g = n & 1023;
  wih16[idx] = f2b(w[g*256 + k]);
  if (idx < 2048) {
    bias[idx] = (idx < 1024) ? (bif[idx] + bhf[idx]) : (bib[idx-1024] + bhb[idx-1024]);
  }
}

// ---- prep: pack w_hh for lstm3's (j,ks,gate,pair) assignment ----
// wph[dir][r][tid]: tid = j*4+ks, r = g*32+p -> f16pair( w[g*256+j][ks*64+2p], w[..+1] )
__global__ void prep_wph2(const float* __restrict__ whf, const float* __restrict__ whb,
                          uint32_t* __restrict__ wph){
  int idx = blockIdx.x*256 + threadIdx.x;       // < 2*128*1024
  int dir = idx >> 17;
  int rem = idx & 131071;
  int r = rem >> 10;        // 0..127
  int tid = rem & 1023;
  int g = r >> 5, p = r & 31;
  int j = tid >> 2, ks = tid & 3;
  const float* w = dir ? whb : whf;
  const float* row = w + (size_t)(g*256 + j)*256 + ks*64 + 2*p;
  _Float16 lo = (_Float16)row[0];
  _Float16 hi = (_Float16)row[1];
  uint16_t l16 = __builtin_bit_cast(uint16_t, lo);
  uint16_t h16 = __builtin_bit_cast(uint16_t, hi);
  wph[idx] = (uint32_t)l16 | ((uint32_t)h16 << 16);
}

// ---- input projection via MFMA: xg[m][j][gate] = emb[tok(m)] . w_ih[n] + bias[n] ----
// Gate-interleaved output layout: per token, unit j's (xi,xf,xg,xo) contiguous.
__global__ __launch_bounds__(256) void inproj_mfma(const int* __restrict__ inp,
    const float* __restrict__ emb, const uint16_t* __restrict__ wih16,
    const float* __restrict__ bias, uint16_t* __restrict__ xgf,
    uint16_t* __restrict__ xgb){
  __shared__ uint16_t As[64][72];    // A[m][k] bf16, +8 pad
  __shared__ uint16_t Bs[128][72];   // B^T[c][k] = w_ih[n0+c][k] bf16, +8 pad
  __shared__ int toks[64];
  int bm = blockIdx.x, bn = blockIdx.y;
  int tid = threadIdx.x;
  if (tid < 64) {
    int m = bm*64 + tid;                       // b = m&63, t = m>>6
    toks[tid] = inp[(m & 63)*S_LEN + (m >> 6)];
  }
  __syncthreads();
  int w = tid >> 6, l = tid & 63;
  int lr = l & 15, lg = l >> 4;
  f32x4 acc[8];
#pragma unroll
  for (int cf = 0; cf < 8; ++cf) acc[cf] = (f32x4){0.f,0.f,0.f,0.f};

  int am = tid >> 2, aq = tid & 3;             // A staging: row am, 16 k each
  int bc = tid >> 1, bh = tid & 1;             // B staging: row bc, 32 k each

  for (int k0 = 0; k0 < 256; k0 += 64) {
    {
      const float* asrc = emb + (size_t)toks[am]*256 + k0 + aq*16;
      float4 v0 = *(const float4*)(asrc+0);
      float4 v1 = *(const float4*)(asrc+4);
      float4 v2 = *(const float4*)(asrc+8);
      float4 v3 = *(const float4*)(asrc+12);
      uint16_t t16[16];
      t16[0]=f2b(v0.x); t16[1]=f2b(v0.y); t16[2]=f2b(v0.z); t16[3]=f2b(v0.w);
      t16[4]=f2b(v1.x); t16[5]=f2b(v1.y); t16[6]=f2b(v1.z); t16[7]=f2b(v1.w);
      t16[8]=f2b(v2.x); t16[9]=f2b(v2.y); t16[10]=f2b(v2.z); t16[11]=f2b(v2.w);
      t16[12]=f2b(v3.x); t16[13]=f2b(v3.y); t16[14]=f2b(v3.z); t16[15]=f2b(v3.w);
      *(uint4*)&As[am][aq*16]     = *(uint4*)&t16[0];
      *(uint4*)&As[am][aq*16 + 8] = *(uint4*)&t16[8];
    }
    {
      const uint16_t* bsrc = wih16 + (size_t)(bn*128 + bc)*256 + k0 + bh*32;
      uint4 b0 = *(const uint4*)(bsrc+0);
      uint4 b1 = *(const uint4*)(bsrc+8);
      uint4 b2 = *(const uint4*)(bsrc+16);
      uint4 b3 = *(const uint4*)(bsrc+24);
      *(uint4*)&Bs[bc][bh*32+0]  = b0;
      *(uint4*)&Bs[bc][bh*32+8]  = b1;
      *(uint4*)&Bs[bc][bh*32+16] = b2;
      *(uint4*)&Bs[bc][bh*32+24] = b3;
    }
    __syncthreads();
#pragma unroll
    for (int ks = 0; ks < 2; ++ks) {
      int koff = ks*32 + lg*8;
      bf16x8 a = *(const bf16x8*)&As[16*w + lr][koff];
#pragma unroll
      for (int cf = 0; cf < 8; ++cf) {
        bf16x8 b = *(const bf16x8*)&Bs[cf*16 + lr][koff];
        acc[cf] = __builtin_amdgcn_mfma_f32_16x16x32_bf16(a, b, acc[cf], 0, 0, 0);
      }
    }
    __syncthreads();
  }
  int n0 = bn*128;
  bool back = (n0 >= 1024);
  uint16_t* dst = back ? xgb : xgf;
  int nb0 = back ? (n0 - 1024) : n0;
#pragma unroll
  for (int cf = 0; cf < 8; ++cf) {
    int nc = cf*16 + lr;
    int nd = nb0 + nc;                 // within-dir column
    int gj = (nd & 255)*4 + (nd >> 8); // gate-interleaved position
    float bv = bias[n0 + nc];
#pragma unroll
    for (int r = 0; r < 4; ++r) {
      int m = bm*64 + 16*w + lg*4 + r;
      dst[(size_t)m*1024 + gj] = f2b(acc[cf][r] + bv);
    }
  }
}

// ---- recurrence: one wg per (dir, batch); 1024 threads; tid = j*4+ks ----
// Thread computes all 4 gates of unit j over k-quarter ks (32 pairs/gate).
// Gates i,f,g: 96 pairs in VGPRs. Gate o: 32 pairs (16 uint2 rows) in LDS.
// Quad shuffle-reduce -> full z4 in every lane -> redundant pointwise, 1 barrier/step.
__global__ __launch_bounds__(1024, 4)
void lstm3(const uint32_t* __restrict__ wph,
    const uint16_t* __restrict__ xgf, const uint16_t* __restrict__ xgb,
    __hip_bfloat16* __restrict__ hout){
  int dir = blockIdx.x >> 6;
  int b = blockIdx.x & 63;
  int tid = threadIdx.x;
  int j = tid >> 2, ks = tid & 3;
  __shared__ uint2 wlo[NLDSROW][1024];          // 128 KB: gate-o pairs
  __shared__ __align__(16) _Float16 hs[2][256]; // double-buffered h

  const uint32_t* wp = wph + (size_t)dir*131072 + tid;
  uint32_t wreg[NREG];
#pragma unroll
  for (int r = 0; r < NREG; ++r) wreg[r] = wp[r*1024];
#pragma unroll
  for (int p = 0; p < NLDSROW; ++p) {
    uint2 v;
    v.x = wp[(NREG + 2*p)*1024];
    v.y = wp[(NREG + 2*p + 1)*1024];
    wlo[p][tid] = v;
  }
#pragma unroll
  for (int r = 0; r < NREG; ++r) asm volatile("" : "+v"(wreg[r]));
  asm volatile("" ::: "memory");
  if (ks == 0) hs[0][j] = (_Float16)0.f;
  float c = 0.f;
  const uint16_t* xgp = (dir ? xgb : xgf) + (size_t)b*1024 + j*4;
  __syncthreads();

  int cur = 0;
  int ts0 = dir ? (S_LEN-1) : 0;
  ushort4 xq = *(const ushort4*)(xgp + (size_t)ts0*65536);
  for (int t = 0; t < S_LEN; ++t) {
    int ts = dir ? (S_LEN-1-t) : t;
    // prefetch next step's x4 (hidden under the dot loop)
    ushort4 xnext = xq;
    if (t + 1 < S_LEN) {
      int tn = dir ? (S_LEN-2-t) : (t+1);
      xnext = *(const ushort4*)(xgp + (size_t)tn*65536);
    }
    float zi = 0.f, zf = 0.f, zg = 0.f, zo = 0.f;
    const uint4* hb4 = (const uint4*)hs[cur];    // 16 uint4; thread reads ks*8+q
#pragma unroll
    for (int q = 0; q < 8; ++q) {
      uint4 hq = hb4[ks*8 + q];
      zi = dot2p(wreg[q*4+0],      hq.x, zi);
      zi = dot2p(wreg[q*4+1],      hq.y, zi);
      zi = dot2p(wreg[q*4+2],      hq.z, zi);
      zi = dot2p(wreg[q*4+3],      hq.w, zi);
      zf = dot2p(wreg[32+q*4+0],   hq.x, zf);
      zf = dot2p(wreg[32+q*4+1],   hq.y, zf);
      zf = dot2p(wreg[32+q*4+2],   hq.z, zf);
      zf = dot2p(wreg[32+q*4+3],   hq.w, zf);
      zg = dot2p(wreg[64+q*4+0],   hq.x, zg);
      zg = dot2p(wreg[64+q*4+1],   hq.y, zg);
      zg = dot2p(wreg[64+q*4+2],   hq.z, zg);
      zg = dot2p(wreg[64+q*4+3],   hq.w, zg);
      uint2 wA = wlo[2*q][tid];
      uint2 wB = wlo[2*q+1][tid];
      zo = dot2p(wA.x, hq.x, zo);
      zo = dot2p(wA.y, hq.y, zo);
      zo = dot2p(wB.x, hq.z, zo);
      zo = dot2p(wB.y, hq.w, zo);
    }
    // quad reduce: sum the 4 k-quarter partials (lanes ks=0..3)
#pragma unroll
    for (int off = 1; off <= 2; off <<= 1) {
      zi += __shfl_xor(zi, off);
      zf += __shfl_xor(zf, off);
      zg += __shfl_xor(zg, off);
      zo += __shfl_xor(zo, off);
    }
    // add x (every lane loaded the same x4 for unit j)
    zi += b2f(xq.x); zf += b2f(xq.y); zg += b2f(xq.z); zo += b2f(xq.w);
    float ig = sigf(zi), fg = sigf(zf), gg = tanh_(zg), og = sigf(zo);
    c = fg*c + ig*gg;
    float hj = og * tanh_(c);
    if (ks == 0) {
      hs[cur^1][j] = (_Float16)hj;
      hout[((size_t)ts*BATCH + b)*512 + dir*256 + j] = __float2bfloat16(hj);
    }
    xq = xnext;
    cur ^= 1;
    __syncthreads();
  }
}

// ---- output projection: emissions[t*64+b][j] = h . w_out[j+1] + b_out[j+1] ----
__global__ __launch_bounds__(256) void outproj(const __hip_bfloat16* __restrict__ hb,
    const float* __restrict__ w_out, const float* __restrict__ b_out,
    float* __restrict__ em){
  __shared__ float wsm[NT*512];
  __shared__ float bsm[NT];
  int tid = threadIdx.x;
  for (int i = tid; i < NT*512; i += 256) wsm[i] = w_out[512 + i];  // rows 1..9
  if (tid < NT) bsm[tid] = b_out[1 + tid];
  __syncthreads();
  int wave = tid >> 6, l = tid & 63;
  int m = blockIdx.x*4 + wave;
  const __hip_bfloat16* hp = hb + (size_t)m*512;
  float hv[8];
#pragma unroll
  for (int q = 0; q < 8; ++q) hv[q] = __bfloat162float(hp[l + 64*q]);
  for (int jj = 0; jj < NT; ++jj) {
    float p = 0.f;
#pragma unroll
    for (int q = 0; q < 8; ++q) p += hv[q]*wsm[jj*512 + 64*q + l];
    p = wredsum(p);
    if (l == 0) em[(size_t)m*NT + jj] = p + bsm[jj];
  }
}

// ---- CRF: one wave per batch item; lanes 0..8 hold the 9-state score ----
__global__ __launch_bounds__(64) void crf(const int* __restrict__ tags,
    const float* __restrict__ em, const float* __restrict__ start_t,
    const float* __restrict__ end_t, const float* __restrict__ trans,
    float* __restrict__ part){
  int b = blockIdx.x;
  int l = threadIdx.x;
  float np = 0.f;
  for (int t = l; t < S_LEN; t += 64) {
    int tg = tags[b*S_LEN + t] - 1;
    float e = em[(size_t)(t*BATCH + b)*NT + tg];
    float tr = (t == 0) ? start_t[tg] : trans[(tags[b*S_LEN + t - 1] - 1)*NT + tg];
    np += e + tr;
  }
  float num = wredsum(np);
  num += end_t[tags[b*S_LEN + S_LEN-1] - 1];
  int j = (l < NT) ? l : 0;
  float tj[NT];
#pragma unroll
  for (int i = 0; i < NT; ++i) tj[i] = trans[i*NT + j];
  float sc = start_t[j] + em[(size_t)b*NT + j];
  for (int t = 1; t < S_LEN; ++t) {
    float e = em[(size_t)(t*BATCH + b)*NT + j];
    float m = -1e30f;
    float vals[NT];
#pragma unroll
    for (int i = 0; i < NT; ++i) { float si = __shfl(sc, i); vals[i] = si + tj[i]; m = fmaxf(m, vals[i]); }
    float ssum = 0.f;
#pragma unroll
    for (int i = 0; i < NT; ++i) ssum += __expf(vals[i] - m);
    sc = e + m + __logf(ssum);
  }
  float vj = (l < NT) ? (sc + end_t[l]) : -1e30f;
  float mx = vj;
#pragma unroll
  for (int s2 = 32; s2 > 0; s2 >>= 1) mx = fmaxf(mx, __shfl_xor(mx, s2));
  float es = __expf(vj - mx);
  es = wredsum(es);
  if (l == 0) part[b] = num - (mx + __logf(es));
}

__global__ void finalize(const float* __restrict__ part, float* __restrict__ out){
  float v = part[threadIdx.x];
  v = wredsum(v);
  if (threadIdx.x == 0) out[0] = -(v / 64.f);
}

extern "C" void kernel_launch(void* const* d_in, const int* in_sizes, int n_in,
                              void* d_out, int out_size, void* d_ws, size_t ws_size,
                              hipStream_t stream) {
  (void)in_sizes; (void)n_in; (void)out_size; (void)ws_size;
  const int*   inputs  = (const int*)d_in[0];
  const int*   tags    = (const int*)d_in[1];
  const float* emb     = (const float*)d_in[3];
  const float* w_ih_f  = (const float*)d_in[4];
  const float* w_hh_f  = (const float*)d_in[5];
  const float* b_ih_f  = (const float*)d_in[6];
  const float* b_hh_f  = (const float*)d_in[7];
  const float* w_ih_b  = (const float*)d_in[8];
  const float* w_hh_b  = (const float*)d_in[9];
  const float* b_ih_b  = (const float*)d_in[10];
  const float* b_hh_b  = (const float*)d_in[11];
  const float* w_out   = (const float*)d_in[12];
  const float* b_out   = (const float*)d_in[13];
  const float* start_t = (const float*)d_in[14];
  const float* end_t   = (const float*)d_in[15];
  const float* trans   = (const float*)d_in[16];

  char* ws = (char*)d_ws;
  size_t off = 0;
  auto alloc = [&](size_t bytes) -> void* {
    void* p = ws + off;
    off = (off + bytes + 255) & ~(size_t)255;
    return p;
  };
  uint16_t* xgf = (uint16_t*)alloc((size_t)NTOK*1024*2);
  uint16_t* xgb = (uint16_t*)alloc((size_t)NTOK*1024*2);
  __hip_bfloat16* hbf = (__hip_bfloat16*)alloc((size_t)NTOK*512*2);
  float*    em    = (float*)alloc((size_t)NTOK*NT*4);
  uint16_t* wih16 = (uint16_t*)alloc((size_t)2048*256*2);
  float*    bias  = (float*)alloc((size_t)2048*4);
  uint32_t* wph   = (uint32_t*)alloc((size_t)2*128*1024*4);
  float*    part  = (float*)alloc((size_t)64*4);

  prep2<<<2048, 256, 0, stream>>>(w_ih_f, w_ih_b, b_ih_f, b_hh_f, b_ih_b, b_hh_b, wih16, bias);
  prep_wph2<<<1024, 256, 0, stream>>>(w_hh_f, w_hh_b, wph);
  inproj_mfma<<<dim3(256, 16), 256, 0, stream>>>(inputs, emb, wih16, bias, xgf, xgb);
  lstm3<<<128, 1024, 0, stream>>>(wph, xgf, xgb, hbf);
  outproj<<<4096, 256, 0, stream>>>(hbf, w_out, b_out, em);
  crf<<<64, 64, 0, stream>>>(tags, em, start_t, end_t, trans, part);
  finalize<<<1, 64, 0, stream>>>(part, (float*)d_out);
}

// Round 6
// 749.354 us; speedup vs baseline: 1.0233x; 1.0233x over previous
//
#include <hip/hip_runtime.h>
#include <hip/hip_bf16.h>
#include <stdint.h>

#define S_LEN 256
#define BATCH 64
#define HD 256
#define NT 9
#define NTOK (S_LEN*BATCH)   // 16384

#define NREG 208             // w_hh pairs in VGPRs per thread (cols 0..5 full + col6 pairs 0..15)
#define NWL 12               // uint4 LDS rows (48 pairs: col6 pairs 16..31 + col7 all 32)

typedef _Float16 hf2 __attribute__((ext_vector_type(2)));
typedef short bf16x8 __attribute__((ext_vector_type(8)));
typedef float f32x4 __attribute__((ext_vector_type(4)));

__device__ __forceinline__ float sigf(float x){ return 1.f/(1.f+__expf(-x)); }
__device__ __forceinline__ float tanh_(float x){ return 1.f - 2.f/(__expf(2.f*x)+1.f); }
__device__ __forceinline__ float wredsum(float v){
#pragma unroll
  for (int s = 32; s > 0; s >>= 1) v += __shfl_xor(v, s);
  return v;
}
__device__ __forceinline__ uint16_t f2b(float f){
  __hip_bfloat16 h = __float2bfloat16(f);
  return *(uint16_t*)&h;
}
__device__ __forceinline__ float b2f(uint16_t u){
  union{uint32_t i; float f;} a; a.i = ((uint32_t)u)<<16; return a.f;
}

__device__ __forceinline__ float dot2p(uint32_t w, uint32_t h, float acc){
#if __has_builtin(__builtin_amdgcn_fdot2)
  return __builtin_amdgcn_fdot2(__builtin_bit_cast(hf2, w), __builtin_bit_cast(hf2, h), acc, false);
#else
  hf2 wv = __builtin_bit_cast(hf2, w), hv = __builtin_bit_cast(hf2, h);
  return acc + (float)wv.x*(float)hv.x + (float)wv.y*(float)hv.y;
#endif
}

// ---- prep: wih16[n][k] = bf16(w_ih_dir[g][k]) (n = dir*1024+g); bias[n] = b_ih+b_hh ----
__global__ void prep2(const float* __restrict__ wihf, const float* __restrict__ wihb,
                      const float* __restrict__ bif, const float* __restrict__ bhf,
                      const float* __restrict__ bib, const float* __restrict__ bhb,
                      uint16_t* __restrict__ wih16, float* __restrict__ bias){
  int idx = blockIdx.x*256 + threadIdx.x;       // < 2048*256
  int n = idx >> 8;
  int k = idx & 255;
  const float* w = (n < 1024) ? wihf : wihb;
  int g = n & 1023;
  wih16[idx] = f2b(w[g*256 + k]);
  if (idx < 2048) {
    bias[idx] = (idx < 1024) ? (bif[idx] + bhf[idx]) : (bib[idx-1024] + bhb[idx-1024]);
  }
}

// ---- prep: pack w_hh for lstm4's (j2, ks) assignment ----
// tid = j2*4+ks (512 threads). Thread owns 8 cols: units {2j2, 2j2+1} x 4 gates,
// k-quarter ks (32 pairs/col). col c = g*2+u. r-index: r<192: c=r>>5,p=r&31;
// 192..207: col6 p=r-192; 208..223: col6 p=r-192; 224..255: col7 p=r-224.
__global__ void prep_wph3(const float* __restrict__ whf, const float* __restrict__ whb,
                          uint32_t* __restrict__ wph){
  int idx = blockIdx.x*256 + threadIdx.x;       // < 2*256*512
  int dir = idx >> 17;
  int rem = idx & 131071;
  int r = rem >> 9;         // 0..255
  int tid = rem & 511;
  int j2 = tid >> 2, ks = tid & 3;
  int c, p;
  if (r < 192)      { c = r >> 5; p = r & 31; }
  else if (r < 224) { c = 6; p = r - 192; }
  else              { c = 7; p = r - 224; }
  int g = c >> 1, u = c & 1;
  int j = 2*j2 + u;
  int k = ks*64 + 2*p;
  const float* w = dir ? whb : whf;
  const float* row = w + (size_t)(g*256 + j)*256 + k;
  _Float16 lo = (_Float16)row[0];
  _Float16 hi = (_Float16)row[1];
  uint16_t l16 = __builtin_bit_cast(uint16_t, lo);
  uint16_t h16 = __builtin_bit_cast(uint16_t, hi);
  wph[idx] = (uint32_t)l16 | ((uint32_t)h16 << 16);
}

// ---- input projection via MFMA: xg[m][j*4+g] = emb[tok(m)] . w_ih[n] + bias[n] ----
__global__ __launch_bounds__(256) void inproj_mfma(const int* __restrict__ inp,
    const float* __restrict__ emb, const uint16_t* __restrict__ wih16,
    const float* __restrict__ bias, uint16_t* __restrict__ xgf,
    uint16_t* __restrict__ xgb){
  __shared__ uint16_t As[64][72];    // A[m][k] bf16, +8 pad
  __shared__ uint16_t Bs[128][72];   // B^T[c][k] = w_ih[n0+c][k] bf16, +8 pad
  __shared__ int toks[64];
  int bm = blockIdx.x, bn = blockIdx.y;
  int tid = threadIdx.x;
  if (tid < 64) {
    int m = bm*64 + tid;                       // b = m&63, t = m>>6
    toks[tid] = inp[(m & 63)*S_LEN + (m >> 6)];
  }
  __syncthreads();
  int w = tid >> 6, l = tid & 63;
  int lr = l & 15, lg = l >> 4;
  f32x4 acc[8];
#pragma unroll
  for (int cf = 0; cf < 8; ++cf) acc[cf] = (f32x4){0.f,0.f,0.f,0.f};

  int am = tid >> 2, aq = tid & 3;             // A staging: row am, 16 k each
  int bc = tid >> 1, bh = tid & 1;             // B staging: row bc, 32 k each

  for (int k0 = 0; k0 < 256; k0 += 64) {
    {
      const float* asrc = emb + (size_t)toks[am]*256 + k0 + aq*16;
      float4 v0 = *(const float4*)(asrc+0);
      float4 v1 = *(const float4*)(asrc+4);
      float4 v2 = *(const float4*)(asrc+8);
      float4 v3 = *(const float4*)(asrc+12);
      uint16_t t16[16];
      t16[0]=f2b(v0.x); t16[1]=f2b(v0.y); t16[2]=f2b(v0.z); t16[3]=f2b(v0.w);
      t16[4]=f2b(v1.x); t16[5]=f2b(v1.y); t16[6]=f2b(v1.z); t16[7]=f2b(v1.w);
      t16[8]=f2b(v2.x); t16[9]=f2b(v2.y); t16[10]=f2b(v2.z); t16[11]=f2b(v2.w);
      t16[12]=f2b(v3.x); t16[13]=f2b(v3.y); t16[14]=f2b(v3.z); t16[15]=f2b(v3.w);
      *(uint4*)&As[am][aq*16]     = *(uint4*)&t16[0];
      *(uint4*)&As[am][aq*16 + 8] = *(uint4*)&t16[8];
    }
    {
      const uint16_t* bsrc = wih16 + (size_t)(bn*128 + bc)*256 + k0 + bh*32;
      uint4 b0 = *(const uint4*)(bsrc+0);
      uint4 b1 = *(const uint4*)(bsrc+8);
      uint4 b2 = *(const uint4*)(bsrc+16);
      uint4 b3 = *(const uint4*)(bsrc+24);
      *(uint4*)&Bs[bc][bh*32+0]  = b0;
      *(uint4*)&Bs[bc][bh*32+8]  = b1;
      *(uint4*)&Bs[bc][bh*32+16] = b2;
      *(uint4*)&Bs[bc][bh*32+24] = b3;
    }
    __syncthreads();
#pragma unroll
    for (int ks = 0; ks < 2; ++ks) {
      int koff = ks*32 + lg*8;
      bf16x8 a = *(const bf16x8*)&As[16*w + lr][koff];
#pragma unroll
      for (int cf = 0; cf < 8; ++cf) {
        bf16x8 b = *(const bf16x8*)&Bs[cf*16 + lr][koff];
        acc[cf] = __builtin_amdgcn_mfma_f32_16x16x32_bf16(a, b, acc[cf], 0, 0, 0);
      }
    }
    __syncthreads();
  }
  int n0 = bn*128;
  bool back = (n0 >= 1024);
  uint16_t* dst = back ? xgb : xgf;
  int nb0 = back ? (n0 - 1024) : n0;
#pragma unroll
  for (int cf = 0; cf < 8; ++cf) {
    int nc = cf*16 + lr;
    int nd = nb0 + nc;                 // within-dir column
    int gj = (nd & 255)*4 + (nd >> 8); // unit-major, gate-minor position
    float bv = bias[n0 + nc];
#pragma unroll
    for (int r = 0; r < 4; ++r) {
      int m = bm*64 + 16*w + lg*4 + r;
      dst[(size_t)m*1024 + gj] = f2b(acc[cf][r] + bv);
    }
  }
}

// ---- recurrence: one wg per (dir, batch); 512 threads = (j2 in [0,128)) x (ks in [0,4)) ----
// Thread computes 8 gate-cols (units 2j2,2j2+1 x 4 gates) over k-quarter ks.
// 208 pairs in VGPRs (256-cap via launch_bounds(512,2)); 48 pairs in LDS (b128 rows).
// h quarters skewed by 16B -> conflict-free broadcast; quad-shfl z reduce; 1 barrier/step.
__global__ __launch_bounds__(512, 2)
void lstm4(const uint32_t* __restrict__ wph,
    const uint16_t* __restrict__ xgf, const uint16_t* __restrict__ xgb,
    __hip_bfloat16* __restrict__ hout){
  int dir = blockIdx.x >> 6;
  int b = blockIdx.x & 63;
  int tid = threadIdx.x;
  int j2 = tid >> 2, ks = tid & 3;
  __shared__ uint4 wl[NWL][512];                  // 96 KB
  __shared__ __align__(16) _Float16 hs[2][4][72]; // skewed quarters (+8 halfs pad)

  const uint32_t* wp = wph + (size_t)dir*131072 + tid;
  uint32_t wreg[NREG];
#pragma unroll
  for (int r = 0; r < NREG; ++r) wreg[r] = wp[r*512];
#pragma unroll
  for (int q = 0; q < NWL; ++q) {
    uint4 v;
    v.x = wp[(NREG + 4*q + 0)*512];
    v.y = wp[(NREG + 4*q + 1)*512];
    v.z = wp[(NREG + 4*q + 2)*512];
    v.w = wp[(NREG + 4*q + 3)*512];
    wl[q][tid] = v;
  }
#pragma unroll
  for (int r = 0; r < NREG; ++r) asm volatile("" : "+v"(wreg[r]));
  asm volatile("" ::: "memory");
  if (tid < 256) hs[0][tid >> 6][tid & 63] = (_Float16)0.f;
  float c0 = 0.f, c1 = 0.f;
  const uint16_t* xgp = (dir ? xgb : xgf) + (size_t)b*1024 + j2*8;
  __syncthreads();

  int cur = 0;
  for (int t = 0; t < S_LEN; ++t) {
    int ts = dir ? (S_LEN-1-t) : t;
    uint4 xq = *(const uint4*)(xgp + (size_t)ts*65536);   // latency hides under dots
    float zc[8] = {0.f,0.f,0.f,0.f,0.f,0.f,0.f,0.f};
    const uint4* hp = (const uint4*)&hs[cur][ks][0];
#pragma unroll
    for (int q = 0; q < 8; ++q) {
      uint4 hq = hp[q];
      uint4 w7 = wl[4+q][tid];
#pragma unroll
      for (int cc = 0; cc < 6; ++cc) {
        zc[cc] = dot2p(wreg[cc*32 + 4*q + 0], hq.x, zc[cc]);
        zc[cc] = dot2p(wreg[cc*32 + 4*q + 1], hq.y, zc[cc]);
        zc[cc] = dot2p(wreg[cc*32 + 4*q + 2], hq.z, zc[cc]);
        zc[cc] = dot2p(wreg[cc*32 + 4*q + 3], hq.w, zc[cc]);
      }
      if (q < 4) {
        zc[6] = dot2p(wreg[192 + 4*q + 0], hq.x, zc[6]);
        zc[6] = dot2p(wreg[192 + 4*q + 1], hq.y, zc[6]);
        zc[6] = dot2p(wreg[192 + 4*q + 2], hq.z, zc[6]);
        zc[6] = dot2p(wreg[192 + 4*q + 3], hq.w, zc[6]);
      } else {
        uint4 w6 = wl[q-4][tid];
        zc[6] = dot2p(w6.x, hq.x, zc[6]);
        zc[6] = dot2p(w6.y, hq.y, zc[6]);
        zc[6] = dot2p(w6.z, hq.z, zc[6]);
        zc[6] = dot2p(w6.w, hq.w, zc[6]);
      }
      zc[7] = dot2p(w7.x, hq.x, zc[7]);
      zc[7] = dot2p(w7.y, hq.y, zc[7]);
      zc[7] = dot2p(w7.z, hq.z, zc[7]);
      zc[7] = dot2p(w7.w, hq.w, zc[7]);
    }
    // reduce the 4 k-quarter partials (lanes ks = 0..3 within each quad)
#pragma unroll
    for (int cc = 0; cc < 8; ++cc) zc[cc] += __shfl_xor(zc[cc], 1);
#pragma unroll
    for (int cc = 0; cc < 8; ++cc) zc[cc] += __shfl_xor(zc[cc], 2);
    // add x: layout [u][g], col c = g*2+u -> xh[(c&1)*4 + (c>>1)]
    uint16_t xh[8];
    *(uint4*)xh = xq;
#pragma unroll
    for (int cc = 0; cc < 8; ++cc) zc[cc] += b2f(xh[(cc & 1)*4 + (cc >> 1)]);
    // pointwise, both units (redundant across the 4 ks lanes)
    float ig0 = sigf(zc[0]), fg0 = sigf(zc[2]), gg0 = tanh_(zc[4]), og0 = sigf(zc[6]);
    c0 = fg0*c0 + ig0*gg0;
    float h0 = og0 * tanh_(c0);
    float ig1 = sigf(zc[1]), fg1 = sigf(zc[3]), gg1 = tanh_(zc[5]), og1 = sigf(zc[7]);
    c1 = fg1*c1 + ig1*gg1;
    float h1 = og1 * tanh_(c1);
    if (ks == 0) {
      hf2 hpair; hpair.x = (_Float16)h0; hpair.y = (_Float16)h1;
      *(uint32_t*)&hs[cur^1][(2*j2) >> 6][(2*j2) & 63] = __builtin_bit_cast(uint32_t, hpair);
      uint32_t hb = (uint32_t)f2b(h0) | ((uint32_t)f2b(h1) << 16);
      *(uint32_t*)&hout[((size_t)ts*BATCH + b)*512 + dir*256 + 2*j2] = hb;
    }
    cur ^= 1;
    __syncthreads();
  }
}

// ---- output projection: emissions[t*64+b][j] = h . w_out[j+1] + b_out[j+1] ----
__global__ __launch_bounds__(256) void outproj(const __hip_bfloat16* __restrict__ hb,
    const float* __restrict__ w_out, const float* __restrict__ b_out,
    float* __restrict__ em){
  __shared__ float wsm[NT*512];
  __shared__ float bsm[NT];
  int tid = threadIdx.x;
  for (int i = tid; i < NT*512; i += 256) wsm[i] = w_out[512 + i];  // rows 1..9
  if (tid < NT) bsm[tid] = b_out[1 + tid];
  __syncthreads();
  int wave = tid >> 6, l = tid & 63;
  int m = blockIdx.x*4 + wave;
  const __hip_bfloat16* hp = hb + (size_t)m*512;
  float hv[8];
#pragma unroll
  for (int q = 0; q < 8; ++q) hv[q] = __bfloat162float(hp[l + 64*q]);
  for (int jj = 0; jj < NT; ++jj) {
    float p = 0.f;
#pragma unroll
    for (int q = 0; q < 8; ++q) p += hv[q]*wsm[jj*512 + 64*q + l];
    p = wredsum(p);
    if (l == 0) em[(size_t)m*NT + jj] = p + bsm[jj];
  }
}

// ---- CRF: one wave per batch item; lanes 0..8 hold the 9-state score ----
__global__ __launch_bounds__(64) void crf(const int* __restrict__ tags,
    const float* __restrict__ em, const float* __restrict__ start_t,
    const float* __restrict__ end_t, const float* __restrict__ trans,
    float* __restrict__ part){
  int b = blockIdx.x;
  int l = threadIdx.x;
  float np = 0.f;
  for (int t = l; t < S_LEN; t += 64) {
    int tg = tags[b*S_LEN + t] - 1;
    float e = em[(size_t)(t*BATCH + b)*NT + tg];
    float tr = (t == 0) ? start_t[tg] : trans[(tags[b*S_LEN + t - 1] - 1)*NT + tg];
    np += e + tr;
  }
  float num = wredsum(np);
  num += end_t[tags[b*S_LEN + S_LEN-1] - 1];
  int j = (l < NT) ? l : 0;
  float tj[NT];
#pragma unroll
  for (int i = 0; i < NT; ++i) tj[i] = trans[i*NT + j];
  float sc = start_t[j] + em[(size_t)b*NT + j];
  for (int t = 1; t < S_LEN; ++t) {
    float e = em[(size_t)(t*BATCH + b)*NT + j];
    float m = -1e30f;
    float vals[NT];
#pragma unroll
    for (int i = 0; i < NT; ++i) { float si = __shfl(sc, i); vals[i] = si + tj[i]; m = fmaxf(m, vals[i]); }
    float ssum = 0.f;
#pragma unroll
    for (int i = 0; i < NT; ++i) ssum += __expf(vals[i] - m);
    sc = e + m + __logf(ssum);
  }
  float vj = (l < NT) ? (sc + end_t[l]) : -1e30f;
  float mx = vj;
#pragma unroll
  for (int s2 = 32; s2 > 0; s2 >>= 1) mx = fmaxf(mx, __shfl_xor(mx, s2));
  float es = __expf(vj - mx);
  es = wredsum(es);
  if (l == 0) part[b] = num - (mx + __logf(es));
}

__global__ void finalize(const float* __restrict__ part, float* __restrict__ out){
  float v = part[threadIdx.x];
  v = wredsum(v);
  if (threadIdx.x == 0) out[0] = -(v / 64.f);
}

extern "C" void kernel_launch(void* const* d_in, const int* in_sizes, int n_in,
                              void* d_out, int out_size, void* d_ws, size_t ws_size,
                              hipStream_t stream) {
  (void)in_sizes; (void)n_in; (void)out_size; (void)ws_size;
  const int*   inputs  = (const int*)d_in[0];
  const int*   tags    = (const int*)d_in[1];
  const float* emb     = (const float*)d_in[3];
  const float* w_ih_f  = (const float*)d_in[4];
  const float* w_hh_f  = (const float*)d_in[5];
  const float* b_ih_f  = (const float*)d_in[6];
  const float* b_hh_f  = (const float*)d_in[7];
  const float* w_ih_b  = (const float*)d_in[8];
  const float* w_hh_b  = (const float*)d_in[9];
  const float* b_ih_b  = (const float*)d_in[10];
  const float* b_hh_b  = (const float*)d_in[11];
  const float* w_out   = (const float*)d_in[12];
  const float* b_out   = (const float*)d_in[13];
  const float* start_t = (const float*)d_in[14];
  const float* end_t   = (const float*)d_in[15];
  const float* trans   = (const float*)d_in[16];

  char* ws = (char*)d_ws;
  size_t off = 0;
  auto alloc = [&](size_t bytes) -> void* {
    void* p = ws + off;
    off = (off + bytes + 255) & ~(size_t)255;
    return p;
  };
  uint16_t* xgf = (uint16_t*)alloc((size_t)NTOK*1024*2);
  uint16_t* xgb = (uint16_t*)alloc((size_t)NTOK*1024*2);
  __hip_bfloat16* hbf = (__hip_bfloat16*)alloc((size_t)NTOK*512*2);
  float*    em    = (float*)alloc((size_t)NTOK*NT*4);
  uint16_t* wih16 = (uint16_t*)alloc((size_t)2048*256*2);
  float*    bias  = (float*)alloc((size_t)2048*4);
  uint32_t* wph   = (uint32_t*)alloc((size_t)2*256*512*4);
  float*    part  = (float*)alloc((size_t)64*4);

  prep2<<<2048, 256, 0, stream>>>(w_ih_f, w_ih_b, b_ih_f, b_hh_f, b_ih_b, b_hh_b, wih16, bias);
  prep_wph3<<<1024, 256, 0, stream>>>(w_hh_f, w_hh_b, wph);
  inproj_mfma<<<dim3(256, 16), 256, 0, stream>>>(inputs, emb, wih16, bias, xgf, xgb);
  lstm4<<<128, 512, 0, stream>>>(wph, xgf, xgb, hbf);
  outproj<<<4096, 256, 0, stream>>>(hbf, w_out, b_out, em);
  crf<<<64, 64, 0, stream>>>(tags, em, start_t, end_t, trans, part);
  finalize<<<1, 64, 0, stream>>>(part, (float*)d_out);
}